// Round 1
// baseline (2278.377 us; speedup 1.0000x reference)
//
#include <hip/hip_runtime.h>
#include <math.h>

#define NN 50000
#define NE 1600000
#define NG 256
#define IND 128
#define HID 64
#define NREL 3
#define SLOPE 0.2f
#define XRS 192        // XR row stride (3 relations * 64, 16B-aligned rows)
#define NRS 832        // node_rep row stride = 13*64

__device__ __forceinline__ float wred_max(float v){
  #pragma unroll
  for (int o = 32; o; o >>= 1) v = fmaxf(v, __shfl_xor(v, o));
  return v;
}
__device__ __forceinline__ float wred_sum(float v){
  #pragma unroll
  for (int o = 32; o; o >>= 1) v += __shfl_xor(v, o);
  return v;
}

// ---- CSR build --------------------------------------------------------------

__global__ void hist_kernel(const int* __restrict__ dst, int* __restrict__ cnts){
  int e = blockIdx.x * blockDim.x + threadIdx.x;
  if (e < NE) atomicAdd(&cnts[dst[e]], 1);
}

__global__ void scan_kernel(const int* __restrict__ cnts, int* __restrict__ rowp){
  __shared__ int buf[1024];
  __shared__ int carry_s;
  int tid = threadIdx.x;
  if (tid == 0) carry_s = 0;
  __syncthreads();
  for (int base = 0; base < NN; base += 1024){
    int i = base + tid;
    int v = (i < NN) ? cnts[i] : 0;
    buf[tid] = v;
    __syncthreads();
    for (int o = 1; o < 1024; o <<= 1){
      int t = (tid >= o) ? buf[tid - o] : 0;
      __syncthreads();
      buf[tid] += t;
      __syncthreads();
    }
    int carry = carry_s;
    if (i < NN) rowp[i] = carry + buf[tid] - v;   // exclusive
    __syncthreads();
    if (tid == 1023) carry_s = carry + buf[1023];
    __syncthreads();
  }
  if (tid == 0) rowp[NN] = carry_s;
}

__global__ void scatter_kernel(const int* __restrict__ src, const int* __restrict__ dst,
                               const int* __restrict__ et, const int* __restrict__ rowp,
                               int* __restrict__ fill, int* __restrict__ csr){
  int e = blockIdx.x * blockDim.x + threadIdx.x;
  if (e >= NE) return;
  int d = dst[e];
  int pos = atomicAdd(&fill[d], 1);
  csr[rowp[d] + pos] = src[e] | (et[e] << 24);
}

// graph boundaries from sorted batch_index: gst[g] = first node with batch >= g
__global__ void gstart_kernel(const int* __restrict__ batch, int* __restrict__ gst){
  int n = blockIdx.x * blockDim.x + threadIdx.x;
  if (n > NN) return;
  int bc = (n < NN) ? batch[n] : NG;
  int bp = (n == 0) ? -1 : batch[n - 1];
  for (int g = bp + 1; g <= bc; ++g) gst[g] = n;
}

// ---- per-layer weight repack: Wcat[k][r*64+h] = W[r][k][h] ------------------

__global__ void prep_wcat(const float* __restrict__ W, float* __restrict__ Wcat, int K){
  int tid = blockIdx.x * blockDim.x + threadIdx.x;
  if (tid >= NREL * K * HID) return;
  int h = tid & 63;
  int k = (tid >> 6) % K;
  int r = tid / (K * HID);
  Wcat[k * XRS + r * HID + h] = W[tid];
}

// ---- fp32 GEMM: XR[n][r*64+h] = sum_k x[n][k] * Wcat[k][r*64+h] -------------
// plus epilogue: QK[n][r] = xr_r[n]·q ; QK[n][3+r] = xr_r[n]·k
__global__ __launch_bounds__(256) void mm_kernel(
    const float* __restrict__ x, int ldx, int K,
    const float* __restrict__ Wcat, const float* __restrict__ qv, const float* __restrict__ kv,
    float* __restrict__ XR, float* __restrict__ QK){
  __shared__ float As[16][68];  // As[k][row] (transposed x tile)
  __shared__ float Bs[16][68];  // Bs[k][col]
  int tid = threadIdx.x;
  int tx = tid & 15, ty = tid >> 4;
  int row0 = blockIdx.x * 64;
  int col0 = blockIdx.y * 64;          // relation r = blockIdx.y
  float acc[4][4] = {};
  int lr = tid >> 2, lc = (tid & 3) << 2;
  int br = tid >> 4, bc = (tid & 15) << 2;
  for (int k0 = 0; k0 < K; k0 += 16){
    float4 av = make_float4(0.f, 0.f, 0.f, 0.f);
    if (row0 + lr < NN) av = *(const float4*)(x + (size_t)(row0 + lr) * ldx + k0 + lc);
    As[lc + 0][lr] = av.x; As[lc + 1][lr] = av.y; As[lc + 2][lr] = av.z; As[lc + 3][lr] = av.w;
    *(float4*)&Bs[br][bc] = *(const float4*)(Wcat + (size_t)(k0 + br) * XRS + col0 + bc);
    __syncthreads();
    #pragma unroll
    for (int kk = 0; kk < 16; ++kk){
      float4 a4 = *(float4*)&As[kk][ty << 2];
      float4 b4 = *(float4*)&Bs[kk][tx << 2];
      float aa[4] = {a4.x, a4.y, a4.z, a4.w};
      float bb[4] = {b4.x, b4.y, b4.z, b4.w};
      #pragma unroll
      for (int i = 0; i < 4; ++i)
        #pragma unroll
        for (int j = 0; j < 4; ++j)
          acc[i][j] = fmaf(aa[i], bb[j], acc[i][j]);
    }
    __syncthreads();
  }
  #pragma unroll
  for (int i = 0; i < 4; ++i){
    int row = row0 + (ty << 2) + i;
    if (row < NN)
      *(float4*)(XR + (size_t)row * XRS + col0 + (tx << 2)) =
          make_float4(acc[i][0], acc[i][1], acc[i][2], acc[i][3]);
  }
  // epilogue: per-thread partial dots with q,k then cross-tx reduction in LDS
  float q4[4], k4[4];
  #pragma unroll
  for (int j = 0; j < 4; ++j){ q4[j] = qv[(tx << 2) + j]; k4[j] = kv[(tx << 2) + j]; }
  float pq[4] = {0,0,0,0}, pk[4] = {0,0,0,0};
  #pragma unroll
  for (int i = 0; i < 4; ++i)
    #pragma unroll
    for (int j = 0; j < 4; ++j){
      pq[i] = fmaf(acc[i][j], q4[j], pq[i]);
      pk[i] = fmaf(acc[i][j], k4[j], pk[i]);
    }
  float* rq = &As[0][0];   // reuse as [64][17]
  float* rk = &Bs[0][0];
  __syncthreads();
  #pragma unroll
  for (int i = 0; i < 4; ++i){
    rq[((ty << 2) + i) * 17 + tx] = pq[i];
    rk[((ty << 2) + i) * 17 + tx] = pk[i];
  }
  __syncthreads();
  if (tid < 64){
    int row = row0 + tid;
    float sq = 0.f, sk = 0.f;
    #pragma unroll
    for (int t = 0; t < 16; ++t){ sq += rq[tid * 17 + t]; sk += rk[tid * 17 + t]; }
    if (row < NN){
      QK[row * 8 + blockIdx.y] = sq;
      QK[row * 8 + 3 + blockIdx.y] = sk;
    }
  }
}

// ---- edge softmax + aggregation: one wave per dst node ----------------------

__global__ __launch_bounds__(256) void edge_kernel(
    const float* __restrict__ XR, const float* __restrict__ QK,
    const int* __restrict__ csr, const int* __restrict__ rowp,
    const float* __restrict__ bias, float* __restrict__ out){
  int wid = blockIdx.x * 4 + (threadIdx.x >> 6);
  int lane = threadIdx.x & 63;
  if (wid >= NN) return;
  int beg = rowp[wid], end = rowp[wid + 1];
  float bv = bias[lane];
  float* op = out + (size_t)wid * NRS + lane;
  if (beg == end){ *op = bv; return; }
  float q0 = QK[wid * 8], q1 = QK[wid * 8 + 1], q2 = QK[wid * 8 + 2];
  // pass 1: online softmax stats (m, s) over incoming edges
  float m = -INFINITY, s = 0.f;
  for (int c = beg; c < end; c += 64){
    int idx = c + lane;
    float l = -INFINITY;
    if (idx < end){
      int pk = csr[idx];
      int sn = pk & 0xFFFFFF, et = pk >> 24;
      float lg = (et == 0 ? q0 : (et == 1 ? q1 : q2)) + QK[sn * 8 + 3 + et];
      l = lg >= 0.f ? lg : lg * SLOPE;
    }
    float mnew = fmaxf(m, wred_max(l));
    float ps = wred_sum((idx < end) ? __expf(l - mnew) : 0.f);
    s = s * __expf(m - mnew) + ps;
    m = mnew;
  }
  float inv = 1.f / (s + 1e-16f);
  // pass 2: weighted gather-accumulate, lane = feature
  float acc = 0.f;
  for (int c = beg; c < end; c += 64){
    int idx = c + lane;
    int off = 0; float wgt = 0.f;
    if (idx < end){
      int pk = csr[idx];
      int sn = pk & 0xFFFFFF, et = pk >> 24;
      float lg = (et == 0 ? q0 : (et == 1 ? q1 : q2)) + QK[sn * 8 + 3 + et];
      float l = lg >= 0.f ? lg : lg * SLOPE;
      wgt = __expf(l - m) * inv;
      off = sn * XRS + et * HID;
    }
    int cnt = min(64, end - c);
    #pragma unroll 4
    for (int j = 0; j < cnt; ++j){
      float wj = __uint_as_float(__builtin_amdgcn_readlane(__float_as_uint(wgt), j));
      int oj = __builtin_amdgcn_readlane(off, j);
      acc = fmaf(wj, XR[oj + lane], acc);
    }
  }
  *op = acc + bv;
}

// ---- graph-level softmax aggregation ---------------------------------------

__global__ void agg_kernel(const float* __restrict__ nr, const int* __restrict__ gst,
                           const float* __restrict__ tp, float* __restrict__ out){
  int g = blockIdx.x;
  int s = gst[g], e = gst[g + 1];
  float tval = tp[0];
  for (int f = threadIdx.x; f < NRS; f += 256){
    float m = -INFINITY;
    for (int n = s; n < e; ++n) m = fmaxf(m, nr[(size_t)n * NRS + f] * tval);
    float ss = 0.f, acc = 0.f;
    for (int n = s; n < e; ++n){
      float v = nr[(size_t)n * NRS + f];
      float ee = __expf(v * tval - m);
      ss += ee; acc = fmaf(v, ee, acc);
    }
    out[(size_t)g * NRS + f] = acc / (ss + 1e-16f);
  }
}

// ---- orchestration ----------------------------------------------------------

extern "C" void kernel_launch(void* const* d_in, const int* in_sizes, int n_in,
                              void* d_out, int out_size, void* d_ws, size_t ws_size,
                              hipStream_t stream){
  const float* x0   = (const float*)d_in[0];
  const int*   eidx = (const int*)d_in[1];
  const int*   etyp = (const int*)d_in[2];
  const int*   batch= (const int*)d_in[3];
  const float* Wf   = (const float*)d_in[4];
  const float* qf   = (const float*)d_in[5];
  const float* kf   = (const float*)d_in[6];
  const float* bf   = (const float*)d_in[7];
  const float* Ws   = (const float*)d_in[8];
  const float* qs   = (const float*)d_in[9];
  const float* ks   = (const float*)d_in[10];
  const float* bs   = (const float*)d_in[11];
  const float* tp   = (const float*)d_in[12];

  float* gout = (float*)d_out;                 // [256][832]
  float* nrep = gout + (size_t)NG * NRS;       // [50000][832]

  char* w = (char*)d_ws;
  float* XR   = (float*)w;  w += (size_t)NN * XRS * 4;        // 38.4 MB
  float* QK   = (float*)w;  w += (size_t)NN * 8 * 4;          // 1.6 MB
  float* Wcat = (float*)w;  w += (size_t)IND * XRS * 4;       // 98 KB
  int*   rowp = (int*)w;    w += (size_t)(NN + 2) * 4;
  int*   cnts = (int*)w;    w += (size_t)NN * 4;
  int*   gst  = (int*)w;    w += (size_t)(NG + 2) * 4;
  int*   csr  = (int*)w;    w += (size_t)NE * 4;              // 6.4 MB

  const int* srcv = eidx;
  const int* dstv = eidx + NE;

  // CSR by dst + graph boundaries (once per call, reused by all 13 layers)
  hipMemsetAsync(cnts, 0, (size_t)NN * 4, stream);
  hist_kernel<<<(NE + 255) / 256, 256, 0, stream>>>(dstv, cnts);
  scan_kernel<<<1, 1024, 0, stream>>>(cnts, rowp);
  hipMemsetAsync(cnts, 0, (size_t)NN * 4, stream);
  scatter_kernel<<<(NE + 255) / 256, 256, 0, stream>>>(srcv, dstv, etyp, rowp, cnts, csr);
  gstart_kernel<<<(NN + 256) / 256, 256, 0, stream>>>(batch, gst);

  for (int l = 0; l < 13; ++l){
    int K = (l == 0) ? IND : HID;
    const float* W  = (l == 0) ? Wf : (Ws + (size_t)(l - 1) * NREL * HID * HID);
    const float* q  = (l == 0) ? qf : (qs + (size_t)(l - 1) * HID);
    const float* kv = (l == 0) ? kf : (ks + (size_t)(l - 1) * HID);
    const float* b  = (l == 0) ? bf : (bs + (size_t)(l - 1) * HID);
    const float* x  = (l == 0) ? x0 : (nrep + (size_t)(l - 1) * HID);
    int ldx = (l == 0) ? IND : NRS;
    int tot = NREL * K * HID;
    prep_wcat<<<(tot + 255) / 256, 256, 0, stream>>>(W, Wcat, K);
    dim3 g((NN + 63) / 64, 3);
    mm_kernel<<<g, 256, 0, stream>>>(x, ldx, K, Wcat, q, kv, XR, QK);
    edge_kernel<<<(NN + 3) / 4, 256, 0, stream>>>(XR, QK, csr, rowp, b, nrep + (size_t)l * HID);
  }
  agg_kernel<<<NG, 256, 0, stream>>>(nrep, gst, tp, gout);
}

// Round 2
// 1993.687 us; speedup vs baseline: 1.1428x; 1.1428x over previous
//
#include <hip/hip_runtime.h>
#include <math.h>

#define NN 50000
#define NE 1600000
#define NG 256
#define IND 128
#define HID 64
#define NREL 3
#define SLOPE 0.2f
#define XRS 192        // XR row stride (3 relations * 64, 16B-aligned rows)
#define NRS 832        // node_rep row stride = 13*64

__device__ __forceinline__ float wred_max(float v){
  #pragma unroll
  for (int o = 32; o; o >>= 1) v = fmaxf(v, __shfl_xor(v, o));
  return v;
}
__device__ __forceinline__ float wred_sum(float v){
  #pragma unroll
  for (int o = 32; o; o >>= 1) v += __shfl_xor(v, o);
  return v;
}

// ---- CSR build --------------------------------------------------------------

__global__ void hist_kernel(const int* __restrict__ dst, int* __restrict__ cnts){
  int e = blockIdx.x * blockDim.x + threadIdx.x;
  if (e < NE) atomicAdd(&cnts[dst[e]], 1);
}

__global__ void scan_kernel(const int* __restrict__ cnts, int* __restrict__ rowp){
  __shared__ int buf[1024];
  __shared__ int carry_s;
  int tid = threadIdx.x;
  if (tid == 0) carry_s = 0;
  __syncthreads();
  for (int base = 0; base < NN; base += 1024){
    int i = base + tid;
    int v = (i < NN) ? cnts[i] : 0;
    buf[tid] = v;
    __syncthreads();
    for (int o = 1; o < 1024; o <<= 1){
      int t = (tid >= o) ? buf[tid - o] : 0;
      __syncthreads();
      buf[tid] += t;
      __syncthreads();
    }
    int carry = carry_s;
    if (i < NN) rowp[i] = carry + buf[tid] - v;   // exclusive
    __syncthreads();
    if (tid == 1023) carry_s = carry + buf[1023];
    __syncthreads();
  }
  if (tid == 0) rowp[NN] = carry_s;
}

__global__ void scatter_kernel(const int* __restrict__ src, const int* __restrict__ dst,
                               const int* __restrict__ et, const int* __restrict__ rowp,
                               int* __restrict__ fill, int* __restrict__ csr){
  int e = blockIdx.x * blockDim.x + threadIdx.x;
  if (e >= NE) return;
  int d = dst[e];
  int pos = atomicAdd(&fill[d], 1);
  csr[rowp[d] + pos] = src[e] | (et[e] << 24);
}

// graph boundaries from sorted batch_index: gst[g] = first node with batch >= g
__global__ void gstart_kernel(const int* __restrict__ batch, int* __restrict__ gst){
  int n = blockIdx.x * blockDim.x + threadIdx.x;
  if (n > NN) return;
  int bc = (n < NN) ? batch[n] : NG;
  int bp = (n == 0) ? -1 : batch[n - 1];
  for (int g = bp + 1; g <= bc; ++g) gst[g] = n;
}

// ---- fp32 GEMM: XR[n][r*64+h] = sum_k x[n][k] * W[r][k][h] ------------------
// plus epilogue: QK[n][r] = xr_r[n]·q ; QK[n][3+r] = xr_r[n]·k
__global__ __launch_bounds__(256) void mm_kernel(
    const float* __restrict__ x, int ldx, int K,
    const float* __restrict__ W, const float* __restrict__ qv, const float* __restrict__ kv,
    float* __restrict__ XR, float* __restrict__ QK){
  __shared__ float As[16][68];  // As[k][row] (transposed x tile)
  __shared__ float Bs[16][68];  // Bs[k][col]
  int tid = threadIdx.x;
  int tx = tid & 15, ty = tid >> 4;
  int row0 = blockIdx.x * 64;
  int r = blockIdx.y;                  // relation
  float acc[4][4] = {};
  int lr = tid >> 2, lc = (tid & 3) << 2;
  int br = tid >> 4, bc = (tid & 15) << 2;
  for (int k0 = 0; k0 < K; k0 += 16){
    float4 av = make_float4(0.f, 0.f, 0.f, 0.f);
    if (row0 + lr < NN) av = *(const float4*)(x + (size_t)(row0 + lr) * ldx + k0 + lc);
    As[lc + 0][lr] = av.x; As[lc + 1][lr] = av.y; As[lc + 2][lr] = av.z; As[lc + 3][lr] = av.w;
    *(float4*)&Bs[br][bc] = *(const float4*)(W + ((size_t)r * K + k0 + br) * HID + bc);
    __syncthreads();
    #pragma unroll
    for (int kk = 0; kk < 16; ++kk){
      float4 a4 = *(float4*)&As[kk][ty << 2];
      float4 b4 = *(float4*)&Bs[kk][tx << 2];
      float aa[4] = {a4.x, a4.y, a4.z, a4.w};
      float bb[4] = {b4.x, b4.y, b4.z, b4.w};
      #pragma unroll
      for (int i = 0; i < 4; ++i)
        #pragma unroll
        for (int j = 0; j < 4; ++j)
          acc[i][j] = fmaf(aa[i], bb[j], acc[i][j]);
    }
    __syncthreads();
  }
  #pragma unroll
  for (int i = 0; i < 4; ++i){
    int row = row0 + (ty << 2) + i;
    if (row < NN)
      *(float4*)(XR + (size_t)row * XRS + r * HID + (tx << 2)) =
          make_float4(acc[i][0], acc[i][1], acc[i][2], acc[i][3]);
  }
  // epilogue: per-thread partial dots with q,k then cross-tx reduction in LDS
  float q4[4], k4[4];
  #pragma unroll
  for (int j = 0; j < 4; ++j){ q4[j] = qv[(tx << 2) + j]; k4[j] = kv[(tx << 2) + j]; }
  float pq[4] = {0,0,0,0}, pk[4] = {0,0,0,0};
  #pragma unroll
  for (int i = 0; i < 4; ++i)
    #pragma unroll
    for (int j = 0; j < 4; ++j){
      pq[i] = fmaf(acc[i][j], q4[j], pq[i]);
      pk[i] = fmaf(acc[i][j], k4[j], pk[i]);
    }
  float* rq = &As[0][0];   // reuse as [64][17]
  float* rk = &Bs[0][0];
  __syncthreads();
  #pragma unroll
  for (int i = 0; i < 4; ++i){
    rq[((ty << 2) + i) * 17 + tx] = pq[i];
    rk[((ty << 2) + i) * 17 + tx] = pk[i];
  }
  __syncthreads();
  if (tid < 64){
    int row = row0 + tid;
    float sq = 0.f, sk = 0.f;
    #pragma unroll
    for (int t = 0; t < 16; ++t){ sq += rq[tid * 17 + t]; sk += rk[tid * 17 + t]; }
    if (row < NN){
      QK[row * 8 + r] = sq;
      QK[row * 8 + 3 + r] = sk;
    }
  }
}

// ---- edge softmax + aggregation: one wave per dst node ----------------------

__global__ __launch_bounds__(256) void edge_kernel(
    const float* __restrict__ XR, const float* __restrict__ QK,
    const int* __restrict__ csr, const int* __restrict__ rowp,
    const float* __restrict__ bias, float* __restrict__ out){
  int wid = blockIdx.x * 4 + (threadIdx.x >> 6);
  int lane = threadIdx.x & 63;
  if (wid >= NN) return;
  int beg = rowp[wid], end = rowp[wid + 1];
  float bv = bias[lane];
  float* op = out + (size_t)wid * NRS + lane;
  if (beg == end){ *op = bv; return; }
  float q0 = QK[wid * 8], q1 = QK[wid * 8 + 1], q2 = QK[wid * 8 + 2];
  // pass 1: online softmax stats (m, s) over incoming edges
  float m = -INFINITY, s = 0.f;
  for (int c = beg; c < end; c += 64){
    int idx = c + lane;
    float l = -INFINITY;
    if (idx < end){
      int pk = csr[idx];
      int sn = pk & 0xFFFFFF, et = pk >> 24;
      float lg = (et == 0 ? q0 : (et == 1 ? q1 : q2)) + QK[sn * 8 + 3 + et];
      l = lg >= 0.f ? lg : lg * SLOPE;
    }
    float mnew = fmaxf(m, wred_max(l));
    float ps = wred_sum((idx < end) ? __expf(l - mnew) : 0.f);
    s = s * __expf(m - mnew) + ps;
    m = mnew;
  }
  float inv = 1.f / (s + 1e-16f);
  // pass 2: weighted gather-accumulate, lane = feature
  float acc = 0.f;
  for (int c = beg; c < end; c += 64){
    int idx = c + lane;
    int off = 0; float wgt = 0.f;
    if (idx < end){
      int pk = csr[idx];
      int sn = pk & 0xFFFFFF, et = pk >> 24;
      float lg = (et == 0 ? q0 : (et == 1 ? q1 : q2)) + QK[sn * 8 + 3 + et];
      float l = lg >= 0.f ? lg : lg * SLOPE;
      wgt = __expf(l - m) * inv;
      off = sn * XRS + et * HID;
    }
    int cnt = min(64, end - c);
    #pragma unroll 4
    for (int j = 0; j < cnt; ++j){
      float wj = __uint_as_float(__builtin_amdgcn_readlane(__float_as_uint(wgt), j));
      int oj = __builtin_amdgcn_readlane(off, j);
      acc = fmaf(wj, XR[oj + lane], acc);
    }
  }
  *op = acc + bv;
}

// ---- graph-level softmax aggregation ---------------------------------------
// grid (NG, 13); block 256 = 4 node-parallel waves x 64 features

__global__ __launch_bounds__(256) void agg_kernel(
    const float* __restrict__ nr, const int* __restrict__ gst,
    const float* __restrict__ tp, float* __restrict__ out){
  __shared__ float red[4][64];
  __shared__ float red2[4][64];
  int g = blockIdx.x;
  int lane = threadIdx.x & 63;
  int w = threadIdx.x >> 6;
  int f = blockIdx.y * 64 + lane;
  int s = gst[g], e = gst[g + 1];
  float tval = tp[0];
  float m = -INFINITY;
  for (int n = s + w; n < e; n += 4)
    m = fmaxf(m, nr[(size_t)n * NRS + f] * tval);
  red[w][lane] = m;
  __syncthreads();
  m = fmaxf(fmaxf(red[0][lane], red[1][lane]), fmaxf(red[2][lane], red[3][lane]));
  float ss = 0.f, acc = 0.f;
  for (int n = s + w; n < e; n += 4){
    float v = nr[(size_t)n * NRS + f];
    float ee = __expf(v * tval - m);
    ss += ee; acc = fmaf(v, ee, acc);
  }
  __syncthreads();
  red[w][lane] = ss; red2[w][lane] = acc;
  __syncthreads();
  if (w == 0){
    ss = red[0][lane] + red[1][lane] + red[2][lane] + red[3][lane];
    acc = red2[0][lane] + red2[1][lane] + red2[2][lane] + red2[3][lane];
    out[(size_t)g * NRS + f] = acc / (ss + 1e-16f);
  }
}

// ---- orchestration ----------------------------------------------------------

extern "C" void kernel_launch(void* const* d_in, const int* in_sizes, int n_in,
                              void* d_out, int out_size, void* d_ws, size_t ws_size,
                              hipStream_t stream){
  const float* x0   = (const float*)d_in[0];
  const int*   eidx = (const int*)d_in[1];
  const int*   etyp = (const int*)d_in[2];
  const int*   batch= (const int*)d_in[3];
  const float* Wf   = (const float*)d_in[4];
  const float* qf   = (const float*)d_in[5];
  const float* kf   = (const float*)d_in[6];
  const float* bf   = (const float*)d_in[7];
  const float* Ws   = (const float*)d_in[8];
  const float* qs   = (const float*)d_in[9];
  const float* ks   = (const float*)d_in[10];
  const float* bs   = (const float*)d_in[11];
  const float* tp   = (const float*)d_in[12];

  float* gout = (float*)d_out;                 // [256][832]
  float* nrep = gout + (size_t)NG * NRS;       // [50000][832]

  char* w = (char*)d_ws;
  float* XR   = (float*)w;  w += (size_t)NN * XRS * 4;        // 38.4 MB
  float* QK   = (float*)w;  w += (size_t)NN * 8 * 4;          // 1.6 MB
  int*   rowp = (int*)w;    w += (size_t)(NN + 2) * 4;
  int*   cnts = (int*)w;    w += (size_t)NN * 4;
  int*   gst  = (int*)w;    w += (size_t)(NG + 2) * 4;
  int*   csr  = (int*)w;    w += (size_t)NE * 4;              // 6.4 MB

  const int* srcv = eidx;
  const int* dstv = eidx + NE;

  // CSR by dst + graph boundaries (once per call, reused by all 13 layers)
  hipMemsetAsync(cnts, 0, (size_t)NN * 4, stream);
  hist_kernel<<<(NE + 255) / 256, 256, 0, stream>>>(dstv, cnts);
  scan_kernel<<<1, 1024, 0, stream>>>(cnts, rowp);
  hipMemsetAsync(cnts, 0, (size_t)NN * 4, stream);
  scatter_kernel<<<(NE + 255) / 256, 256, 0, stream>>>(srcv, dstv, etyp, rowp, cnts, csr);
  gstart_kernel<<<(NN + 256) / 256, 256, 0, stream>>>(batch, gst);

  for (int l = 0; l < 13; ++l){
    int K = (l == 0) ? IND : HID;
    const float* W  = (l == 0) ? Wf : (Ws + (size_t)(l - 1) * NREL * HID * HID);
    const float* q  = (l == 0) ? qf : (qs + (size_t)(l - 1) * HID);
    const float* kv = (l == 0) ? kf : (ks + (size_t)(l - 1) * HID);
    const float* b  = (l == 0) ? bf : (bs + (size_t)(l - 1) * HID);
    const float* x  = (l == 0) ? x0 : (nrep + (size_t)(l - 1) * HID);
    int ldx = (l == 0) ? IND : NRS;
    dim3 g((NN + 63) / 64, 3);
    mm_kernel<<<g, 256, 0, stream>>>(x, ldx, K, W, q, kv, XR, QK);
    edge_kernel<<<(NN + 3) / 4, 256, 0, stream>>>(XR, QK, csr, rowp, b, nrep + (size_t)l * HID);
  }
  dim3 ag(NG, 13);
  agg_kernel<<<ag, 256, 0, stream>>>(nrep, gst, tp, gout);
}